// Round 4
// baseline (1080.402 us; speedup 1.0000x reference)
//
#include <hip/hip_runtime.h>
#include <hip/hip_bf16.h>

typedef unsigned int u32;
typedef unsigned short u16;

#define DIMN 256
#define TLEN 256

// ---------------------------------------------------------------------------
// dot2 helper: fp16 pair dot with fp32 accumulate (v_dot2_f32_f16)
// ---------------------------------------------------------------------------
typedef _Float16 half2v __attribute__((ext_vector_type(2)));

__device__ __forceinline__ float dot2f(u32 a, u32 b, float c) {
#if __has_builtin(__builtin_amdgcn_fdot2)
    half2v ah = __builtin_bit_cast(half2v, a);
    half2v bh = __builtin_bit_cast(half2v, b);
    return __builtin_amdgcn_fdot2(ah, bh, c, false);
#else
    half2v ah = __builtin_bit_cast(half2v, a);
    half2v bh = __builtin_bit_cast(half2v, b);
    return c + (float)ah.x * (float)bh.x + (float)ah.y * (float)bh.y;
#endif
}

__device__ __forceinline__ u32 packh2(float lo, float hi) {
    _Float16 l = (_Float16)lo, h = (_Float16)hi;
    u16 lu = __builtin_bit_cast(u16, l);
    u16 hu = __builtin_bit_cast(u16, h);
    return (u32)lu | ((u32)hu << 16);
}

union F4U { float4 f; u32 u[4]; };

// ---------------------------------------------------------------------------
// prep kernels: build P^T, S^T, W^T (fp32) then pack S^T/P^T to half2 pairs
//   Pt[j*256+i] = P[i][j],  P = D^T F D
//   St[j*256+i] = S[i][j],  S = I - (1/a) D^T (A^T A + lam2 I) D
//   Wt[d*256+i] = W[i][d],  W = (1/a) D^T A^T A
// ---------------------------------------------------------------------------
__global__ void prep1(const float* __restrict__ A, const float* __restrict__ D,
                      const float* __restrict__ F, const float* __restrict__ lam2p,
                      float* __restrict__ FD, float* __restrict__ G,
                      float* __restrict__ AD) {
    int gid = blockIdx.x * 256 + threadIdx.x;
    if (gid < 65536) {                   // FD[k][j] = sum_q F[k][q] D[q][j]
        int k = gid >> 8, j = gid & 255;
        float s = 0.f;
        #pragma unroll 8
        for (int q = 0; q < 256; ++q) s += F[k*256+q] * D[q*256+j];
        FD[gid] = s;
    } else if (gid < 131072) {           // G[p][q] = sum_m A[m][p] A[m][q] + lam2*(p==q)
        int g = gid - 65536; int p = g >> 8, q = g & 255;
        float s = (p == q) ? lam2p[0] : 0.f;
        #pragma unroll 8
        for (int m = 0; m < 64; ++m) s += A[m*256+p] * A[m*256+q];
        G[g] = s;
    } else if (gid < 147456) {           // AD[m][i] = sum_k A[m][k] D[k][i]
        int g = gid - 131072; int m = g >> 8, i = g & 255;
        float s = 0.f;
        #pragma unroll 8
        for (int k = 0; k < 256; ++k) s += A[m*256+k] * D[k*256+i];
        AD[g] = s;
    }
}

__global__ void prep2(const float* __restrict__ A, const float* __restrict__ D,
                      const float* __restrict__ alphap,
                      const float* __restrict__ FD, const float* __restrict__ G,
                      const float* __restrict__ AD,
                      float* __restrict__ Pt, float* __restrict__ GD,
                      float* __restrict__ Wt) {
    int gid = blockIdx.x * 256 + threadIdx.x;
    float inva = 1.0f / alphap[0];
    if (gid < 65536) {                   // Pt[j][i] = sum_k D[k][i] FD[k][j]
        int j = gid >> 8, i = gid & 255;
        float s = 0.f;
        #pragma unroll 8
        for (int k = 0; k < 256; ++k) s += D[k*256+i] * FD[k*256+j];
        Pt[gid] = s;
    } else if (gid < 131072) {           // GD[k][j] = sum_q G[k][q] D[q][j]
        int g = gid - 65536; int k = g >> 8, j = g & 255;
        float s = 0.f;
        #pragma unroll 8
        for (int q = 0; q < 256; ++q) s += G[k*256+q] * D[q*256+j];
        GD[g] = s;
    } else {                             // Wt[d][i] = inva * sum_m AD[m][i] A[m][d]
        int g = gid - 131072; int d = g >> 8, i = g & 255;
        float s = 0.f;
        #pragma unroll 8
        for (int m = 0; m < 64; ++m) s += AD[m*256+i] * A[m*256+d];
        Wt[g] = inva * s;
    }
}

__global__ void prep3(const float* __restrict__ D, const float* __restrict__ GD,
                      const float* __restrict__ alphap, float* __restrict__ St) {
    int gid = blockIdx.x * 256 + threadIdx.x;   // 65536 threads
    int j = gid >> 8, i = gid & 255;
    float inva = 1.0f / alphap[0];
    float s = 0.f;
    #pragma unroll 8
    for (int k = 0; k < 256; ++k) s += D[k*256+i] * GD[k*256+j];
    St[gid] = ((i == j) ? 1.0f : 0.0f) - inva * s;
}

// pack: Xh[jp*256+i] = (X[i][2jp], X[i][2jp+1])
__global__ void prep4(const float* __restrict__ St, const float* __restrict__ Pt,
                      u32* __restrict__ Sth, u32* __restrict__ Pth) {
    int gid = blockIdx.x * 256 + threadIdx.x;   // 65536 threads
    int g = gid & 32767;
    int jp = g >> 8, i = g & 255;
    if (gid < 32768)
        Sth[g] = packh2(St[(2*jp)*256 + i], St[(2*jp+1)*256 + i]);
    else
        Pth[g] = packh2(Pt[(2*jp)*256 + i], Pt[(2*jp+1)*256 + i]);
}

// ---------------------------------------------------------------------------
// Z-GEMM: Z[b][t][i] = sum_d Wt[d*256+i] * y[b][d][t], written PACKED fp16:
//   Zh[((b*256+t)*128 + i/2] = (Z[b][t][2*(i/2)], Z[b][t][2*(i/2)+1])
// 128x128 tile per block, 8x8 micro-tile, float4 LDS reads
// ---------------------------------------------------------------------------
__launch_bounds__(256, 2)
__global__ void zgemm(const float* __restrict__ y, const float* __restrict__ Wt,
                      u32* __restrict__ Zh) {
    __shared__ float ys[64][132];    // [dd][tt]
    __shared__ float wsh[64][132];   // [dd][ii]
    const int b  = blockIdx.x;
    const int t0 = (blockIdx.y & 1) * 128;
    const int i0 = (blockIdx.y >> 1) * 128;
    const int tid = threadIdx.x;
    const int tx = tid & 15;   // i-octet
    const int ty = tid >> 4;   // t-octet
    float acc[8][8];           // [c=t][a=i]
    #pragma unroll
    for (int c = 0; c < 8; ++c)
        #pragma unroll
        for (int a = 0; a < 8; ++a) acc[c][a] = 0.f;

    for (int dc = 0; dc < 256; dc += 64) {
        #pragma unroll
        for (int k = 0; k < 8; ++k) {
            int idx = k * 256 + tid;           // 2048 float4 per array
            int row = idx >> 5, col4 = idx & 31;
            float4 yv = *(const float4*)&y[((size_t)b*256 + dc + row)*256 + t0 + col4*4];
            float4 wv = *(const float4*)&Wt[(size_t)(dc + row)*256 + i0 + col4*4];
            *(float4*)&ys[row][col4*4]  = yv;
            *(float4*)&wsh[row][col4*4] = wv;
        }
        __syncthreads();
        #pragma unroll 4
        for (int dd = 0; dd < 64; ++dd) {
            float4 w0 = *(const float4*)&wsh[dd][8*tx];
            float4 w1 = *(const float4*)&wsh[dd][8*tx+4];
            float4 y0 = *(const float4*)&ys[dd][8*ty];
            float4 y1 = *(const float4*)&ys[dd][8*ty+4];
            float wv[8] = {w0.x,w0.y,w0.z,w0.w,w1.x,w1.y,w1.z,w1.w};
            float yv[8] = {y0.x,y0.y,y0.z,y0.w,y1.x,y1.y,y1.z,y1.w};
            #pragma unroll
            for (int c = 0; c < 8; ++c)
                #pragma unroll
                for (int a = 0; a < 8; ++a) acc[c][a] += wv[a] * yv[c];
        }
        __syncthreads();
    }
    #pragma unroll
    for (int c = 0; c < 8; ++c) {
        int t = t0 + 8*ty + c;
        uint4 pk;
        pk.x = packh2(acc[c][0], acc[c][1]);
        pk.y = packh2(acc[c][2], acc[c][3]);
        pk.z = packh2(acc[c][4], acc[c][5]);
        pk.w = packh2(acc[c][6], acc[c][7]);
        *(uint4*)&Zh[((size_t)b*256 + t)*128 + (i0 >> 1) + 4*tx] = pk;
    }
}

// ---------------------------------------------------------------------------
// scan4: 256 blocks (one per batch row) x 1024 threads.
// Thread (i = tid&255, q = tid>>8) holds the q-th K-quarter of S-row-i and
// P-row-i in VGPRs. Z (fp16) lives entirely in LDS (preloaded once); H is
// buffered in LDS and flushed every 16 steps -> no vmcnt drain per barrier.
// ---------------------------------------------------------------------------
__attribute__((amdgpu_waves_per_eu(4, 4)))
__launch_bounds__(1024)
__global__ void scan4(const u32* __restrict__ Sth, const u32* __restrict__ Pth,
                      const u32* __restrict__ Zh,
                      const float* __restrict__ h0, const float* __restrict__ U,
                      const float* __restrict__ lam1p, const float* __restrict__ lam2p,
                      const float* __restrict__ alphap,
                      float* __restrict__ H) {
    __shared__ u32 Zl[32768];                    // 128 KB: whole Z slice, fp16
    __shared__ float Hbuf[16 * DIMN];            // 16 KB: 16 h columns, fp32
    __shared__ __align__(16) _Float16 hb[2][DIMN];
    __shared__ float part[4][DIMN];

    const int tid = threadIdx.x;
    const int i   = tid & 255;
    const int q   = tid >> 8;
    const int b   = blockIdx.x;

    const float inva = 1.0f / alphap[0];
    const float bt   = lam1p[0] * inva;
    const float c2   = lam2p[0] * inva;
    const float ui   = U[i] * bt;

    // matrix row quarters -> registers (coalesced: i consecutive per wave)
    u32 Sq[32], Pq[32];
    #pragma unroll
    for (int jp = 0; jp < 32; ++jp) {
        Sq[jp] = Sth[(q*32 + jp)*256 + i];
        Pq[jp] = Pth[(q*32 + jp)*256 + i];
    }

    // preload this block's Z slice (256 cols x 256 fp16 = 128 KB)
    {
        const u32* Zg = Zh + (size_t)b * 32768;
        #pragma unroll
        for (int k = 0; k < 8; ++k) {
            uint4 v = *(const uint4*)(Zg + k*4096 + tid*4);
            *(uint4*)&Zl[k*4096 + tid*4] = v;
        }
    }
    if (tid < 256) hb[0][i] = (_Float16)h0[i];
    __syncthreads();

    float* Hb = H + (size_t)b * TLEN * DIMN;
    const _Float16* Zhalf = (const _Float16*)Zl;

    int cur = 0;
    #pragma unroll 1
    for (int t = 0; t < TLEN; ++t) {
        // ---- P-phase: partial dot of P-row-quarter with h_pre quarter ----
        {
            const float4* hp = (const float4*)(&hb[cur][q*64]);
            float a0 = 0.f, a1 = 0.f, a2 = 0.f, a3 = 0.f;
            #pragma unroll
            for (int k = 0; k < 8; ++k) {
                F4U u; u.f = hp[k];
                a0 = dot2f(Pq[4*k+0], u.u[0], a0);
                a1 = dot2f(Pq[4*k+1], u.u[1], a1);
                a2 = dot2f(Pq[4*k+2], u.u[2], a2);
                a3 = dot2f(Pq[4*k+3], u.u[3], a3);
            }
            part[q][i] = (a0 + a1) + (a2 + a3);
        }
        __syncthreads();

        float creg = 0.f;
        if (tid < 256) {
            float ph = (part[0][i] + part[1][i]) + (part[2][i] + part[3][i]);
            creg = (float)Zhalf[t*256 + i] + c2 * ph;
            hb[cur ^ 1][i] = (_Float16)ph;
        }
        __syncthreads();

        int buf = cur ^ 1;
        #pragma unroll
        for (int it = 0; it < 4; ++it) {
            {
                const float4* hp = (const float4*)(&hb[buf][q*64]);
                float a0 = 0.f, a1 = 0.f, a2 = 0.f, a3 = 0.f;
                #pragma unroll
                for (int k = 0; k < 8; ++k) {
                    F4U u; u.f = hp[k];
                    a0 = dot2f(Sq[4*k+0], u.u[0], a0);
                    a1 = dot2f(Sq[4*k+1], u.u[1], a1);
                    a2 = dot2f(Sq[4*k+2], u.u[2], a2);
                    a3 = dot2f(Sq[4*k+3], u.u[3], a3);
                }
                part[q][i] = (a0 + a1) + (a2 + a3);
            }
            __syncthreads();
            if (tid < 256) {
                float z = (part[0][i] + part[1][i]) + (part[2][i] + part[3][i]) + creg;
                float aa = fabsf(z) - ui;
                float h = (aa > 0.f) ? copysignf(aa, z) : 0.f;
                hb[buf ^ 1][i] = (_Float16)h;
                if (it == 3) Hbuf[(t & 15)*DIMN + i] = h;
            }
            __syncthreads();
            buf ^= 1;
        }
        cur = buf;           // hb[cur] now holds h_t

        // ---- flush 16 completed h columns to global (coalesced float4) ----
        if ((t & 15) == 15) {
            float4 v = *(const float4*)&Hbuf[tid * 4];
            *(float4*)&Hb[(size_t)(t - 15) * DIMN + tid * 4] = v;
        }
    }
}

// ---------------------------------------------------------------------------
// out-GEMM: out[b][n][t] = sum_d D[n][d] * H[b][t][d]
// 128x128 tile, 8x8 micro-tile; both operands transposed into LDS
// ---------------------------------------------------------------------------
__launch_bounds__(256, 2)
__global__ void ogemm(const float* __restrict__ D, const float* __restrict__ H,
                      float* __restrict__ out) {
    __shared__ float Ds[64][132];   // [dd][nn]
    __shared__ float Hs[64][132];   // [dd][tt]
    const int b  = blockIdx.x;
    const int n0 = (blockIdx.y & 1) * 128;
    const int t0 = (blockIdx.y >> 1) * 128;
    const int tid = threadIdx.x;
    const int tx = tid & 15;   // n-octet
    const int ty = tid >> 4;   // t-octet
    float acc[8][8];           // [a=n][c=t]
    #pragma unroll
    for (int a = 0; a < 8; ++a)
        #pragma unroll
        for (int c = 0; c < 8; ++c) acc[a][c] = 0.f;

    for (int dc = 0; dc < 256; dc += 64) {
        #pragma unroll
        for (int k = 0; k < 8; ++k) {
            int idx = k * 256 + tid;           // 2048 float4 per array
            int row = idx >> 4;                // nn or tt (128 rows)
            int d4  = idx & 15;                // 16 float4 across d-chunk
            float4 dv = *(const float4*)&D[((size_t)(n0 + row))*256 + dc + d4*4];
            float4 hv = *(const float4*)&H[((size_t)b*256 + t0 + row)*256 + dc + d4*4];
            Ds[d4*4+0][row] = dv.x; Ds[d4*4+1][row] = dv.y;
            Ds[d4*4+2][row] = dv.z; Ds[d4*4+3][row] = dv.w;
            Hs[d4*4+0][row] = hv.x; Hs[d4*4+1][row] = hv.y;
            Hs[d4*4+2][row] = hv.z; Hs[d4*4+3][row] = hv.w;
        }
        __syncthreads();
        #pragma unroll 4
        for (int dd = 0; dd < 64; ++dd) {
            float4 d0 = *(const float4*)&Ds[dd][8*tx];
            float4 d1 = *(const float4*)&Ds[dd][8*tx+4];
            float4 h0v = *(const float4*)&Hs[dd][8*ty];
            float4 h1v = *(const float4*)&Hs[dd][8*ty+4];
            float dv[8] = {d0.x,d0.y,d0.z,d0.w,d1.x,d1.y,d1.z,d1.w};
            float hv[8] = {h0v.x,h0v.y,h0v.z,h0v.w,h1v.x,h1v.y,h1v.z,h1v.w};
            #pragma unroll
            for (int a = 0; a < 8; ++a)
                #pragma unroll
                for (int c = 0; c < 8; ++c) acc[a][c] += dv[a] * hv[c];
        }
        __syncthreads();
    }
    #pragma unroll
    for (int a = 0; a < 8; ++a) {
        float* op = &out[((size_t)b*256 + n0 + 8*tx + a)*256 + t0 + 8*ty];
        *(float4*)(op)     = make_float4(acc[a][0], acc[a][1], acc[a][2], acc[a][3]);
        *(float4*)(op + 4) = make_float4(acc[a][4], acc[a][5], acc[a][6], acc[a][7]);
    }
}

// ---------------------------------------------------------------------------
extern "C" void kernel_launch(void* const* d_in, const int* in_sizes, int n_in,
                              void* d_out, int out_size, void* d_ws, size_t ws_size,
                              hipStream_t stream) {
    const float* y     = (const float*)d_in[0];
    const float* A     = (const float*)d_in[1];
    const float* D     = (const float*)d_in[2];
    const float* F     = (const float*)d_in[3];
    const float* lam1  = (const float*)d_in[4];
    const float* lam2  = (const float*)d_in[5];
    const float* alpha = (const float*)d_in[6];
    const float* h0    = (const float*)d_in[7];
    const float* U     = (const float*)d_in[8];
    float* out = (float*)d_out;
    float* ws  = (float*)d_ws;

    // ws layout (element offsets, fp32 words)
    const size_t oZ  = 0;           // Zh: 8.39M u32 packed fp16 (region 16.7M)
    const size_t oH  = 16777216;    // H fp32: 16.7M
    const size_t oWt = 33554432;
    const size_t oSt = 33619968;
    const size_t oPt = 33685504;
    const size_t oFD = 33751040;
    const size_t oG  = 33816576;
    const size_t oGD = 33882112;
    const size_t oAD = 33947648;
    const size_t oSh = 33964032;   // u32 packed half2
    const size_t oPh = 33996800;   // u32 packed half2

    u32*   Zh = (u32*)(ws + oZ);
    float* H  = ws + oH;
    float* Wt = ws + oWt; float* St = ws + oSt; float* Pt = ws + oPt;
    float* FD = ws + oFD; float* G  = ws + oG;  float* GD = ws + oGD;
    float* AD = ws + oAD;
    u32* Sth = (u32*)(ws + oSh);
    u32* Pth = (u32*)(ws + oPh);

    prep1<<<576, 256, 0, stream>>>(A, D, F, lam2, FD, G, AD);
    prep2<<<768, 256, 0, stream>>>(A, D, alpha, FD, G, AD, Pt, GD, Wt);
    prep3<<<256, 256, 0, stream>>>(D, GD, alpha, St);
    prep4<<<256, 256, 0, stream>>>(St, Pt, Sth, Pth);
    {
        dim3 g(256, 4);
        zgemm<<<g, 256, 0, stream>>>(y, Wt, Zh);
    }
    scan4<<<256, 1024, 0, stream>>>(Sth, Pth, Zh, h0, U, lam1, lam2, alpha, H);
    {
        dim3 g(256, 4);
        ogemm<<<g, 256, 0, stream>>>(D, H, out);
    }
}

// Round 5
// 932.337 us; speedup vs baseline: 1.1588x; 1.1588x over previous
//
#include <hip/hip_runtime.h>
#include <hip/hip_bf16.h>

typedef unsigned int u32;
typedef unsigned short u16;

#define DIMN 256
#define TLEN 256

// ---------------------------------------------------------------------------
// helpers
// ---------------------------------------------------------------------------
typedef _Float16 half2v __attribute__((ext_vector_type(2)));

__device__ __forceinline__ float dot2f(u32 a, u32 b, float c) {
#if __has_builtin(__builtin_amdgcn_fdot2)
    half2v ah = __builtin_bit_cast(half2v, a);
    half2v bh = __builtin_bit_cast(half2v, b);
    return __builtin_amdgcn_fdot2(ah, bh, c, false);
#else
    half2v ah = __builtin_bit_cast(half2v, a);
    half2v bh = __builtin_bit_cast(half2v, b);
    return c + (float)ah.x * (float)bh.x + (float)ah.y * (float)bh.y;
#endif
}

__device__ __forceinline__ u32 packh2(float lo, float hi) {
    _Float16 l = (_Float16)lo, h = (_Float16)hi;
    u16 lu = __builtin_bit_cast(u16, l);
    u16 hu = __builtin_bit_cast(u16, h);
    return (u32)lu | ((u32)hu << 16);
}

__device__ __forceinline__ float h2lo(u32 v) {
    return (float)__builtin_bit_cast(half2v, v).x;
}
__device__ __forceinline__ float h2hi(u32 v) {
    return (float)__builtin_bit_cast(half2v, v).y;
}

// sum over the 4 lanes of a quad via DPP quad_perm (VALU-pipe, no LDS)
__device__ __forceinline__ float quad_reduce(float v) {
    int x = __builtin_bit_cast(int, v);
    int y = __builtin_amdgcn_update_dpp(0, x, 0xB1, 0xF, 0xF, true); // [1,0,3,2]
    v += __builtin_bit_cast(float, y);
    x = __builtin_bit_cast(int, v);
    y = __builtin_amdgcn_update_dpp(0, x, 0x4E, 0xF, 0xF, true);     // [2,3,0,1]
    v += __builtin_bit_cast(float, y);
    return v;
}

// ---------------------------------------------------------------------------
// prep kernels: build P^T, S^T, W^T (fp32), then pack S/P for scan5
//   Pt[j*256+i] = P[i][j],  P = D^T F D
//   St[j*256+i] = S[i][j],  S = I - (1/a) D^T (A^T A + lam2 I) D
//   Wt[d*256+i] = W[i][d],  W = (1/a) D^T A^T A
// ---------------------------------------------------------------------------
__global__ void prep1(const float* __restrict__ A, const float* __restrict__ D,
                      const float* __restrict__ F, const float* __restrict__ lam2p,
                      float* __restrict__ FD, float* __restrict__ G,
                      float* __restrict__ AD) {
    int gid = blockIdx.x * 256 + threadIdx.x;
    if (gid < 65536) {                   // FD[k][j] = sum_q F[k][q] D[q][j]
        int k = gid >> 8, j = gid & 255;
        float s = 0.f;
        #pragma unroll 8
        for (int q = 0; q < 256; ++q) s += F[k*256+q] * D[q*256+j];
        FD[gid] = s;
    } else if (gid < 131072) {           // G[p][q] = sum_m A[m][p] A[m][q] + lam2*(p==q)
        int g = gid - 65536; int p = g >> 8, q = g & 255;
        float s = (p == q) ? lam2p[0] : 0.f;
        #pragma unroll 8
        for (int m = 0; m < 64; ++m) s += A[m*256+p] * A[m*256+q];
        G[g] = s;
    } else if (gid < 147456) {           // AD[m][i] = sum_k A[m][k] D[k][i]
        int g = gid - 131072; int m = g >> 8, i = g & 255;
        float s = 0.f;
        #pragma unroll 8
        for (int k = 0; k < 256; ++k) s += A[m*256+k] * D[k*256+i];
        AD[g] = s;
    }
}

__global__ void prep2(const float* __restrict__ A, const float* __restrict__ D,
                      const float* __restrict__ alphap,
                      const float* __restrict__ FD, const float* __restrict__ G,
                      const float* __restrict__ AD,
                      float* __restrict__ Pt, float* __restrict__ GD,
                      float* __restrict__ Wt) {
    int gid = blockIdx.x * 256 + threadIdx.x;
    float inva = 1.0f / alphap[0];
    if (gid < 65536) {                   // Pt[j][i] = sum_k D[k][i] FD[k][j]
        int j = gid >> 8, i = gid & 255;
        float s = 0.f;
        #pragma unroll 8
        for (int k = 0; k < 256; ++k) s += D[k*256+i] * FD[k*256+j];
        Pt[gid] = s;
    } else if (gid < 131072) {           // GD[k][j] = sum_q G[k][q] D[q][j]
        int g = gid - 65536; int k = g >> 8, j = g & 255;
        float s = 0.f;
        #pragma unroll 8
        for (int q = 0; q < 256; ++q) s += G[k*256+q] * D[q*256+j];
        GD[g] = s;
    } else {                             // Wt[d][i] = inva * sum_m AD[m][i] A[m][d]
        int g = gid - 131072; int d = g >> 8, i = g & 255;
        float s = 0.f;
        #pragma unroll 8
        for (int m = 0; m < 64; ++m) s += AD[m*256+i] * A[m*256+d];
        Wt[g] = inva * s;
    }
}

__global__ void prep3(const float* __restrict__ D, const float* __restrict__ GD,
                      const float* __restrict__ alphap, float* __restrict__ St) {
    int gid = blockIdx.x * 256 + threadIdx.x;   // 65536 threads
    int j = gid >> 8, i = gid & 255;
    float inva = 1.0f / alphap[0];
    float s = 0.f;
    #pragma unroll 8
    for (int k = 0; k < 256; ++k) s += D[k*256+i] * GD[k*256+j];
    St[gid] = ((i == j) ? 1.0f : 0.0f) - inva * s;
}

// pack for scan5: thread t=(i2=t>>2, q=t&3) of 512 handles rows 2i2,2i2+1,
// K-quarter q.  Spk[jp*1024 + 2*t + r] = (S[2(t>>2)+r][64(t&3)+2jp], ..+1)
__global__ void prep4(const float* __restrict__ St, const float* __restrict__ Pt,
                      u32* __restrict__ Spk, u32* __restrict__ Ppk) {
    int gid = blockIdx.x * 256 + threadIdx.x;   // 65536 threads
    int idx = gid & 32767;
    int jp  = idx >> 10;
    int rem = idx & 1023;
    int t   = rem >> 1;
    int r   = rem & 1;
    int row = 2*(t >> 2) + r;
    int col = 64*(t & 3) + 2*jp;
    if (gid < 32768)
        Spk[idx] = packh2(St[col*256 + row], St[(col+1)*256 + row]);
    else
        Ppk[idx] = packh2(Pt[col*256 + row], Pt[(col+1)*256 + row]);
}

// ---------------------------------------------------------------------------
// Z-GEMM: Z[b][t][i] = sum_d Wt[d*256+i] * y[b][d][t], written PACKED fp16:
//   Zh[(b*256+t)*128 + i/2] = (Z[b][t][i_even], Z[b][t][i_even+1])
// ---------------------------------------------------------------------------
__launch_bounds__(256, 2)
__global__ void zgemm(const float* __restrict__ y, const float* __restrict__ Wt,
                      u32* __restrict__ Zh) {
    __shared__ float ys[64][132];    // [dd][tt]
    __shared__ float wsh[64][132];   // [dd][ii]
    const int b  = blockIdx.x;
    const int t0 = (blockIdx.y & 1) * 128;
    const int i0 = (blockIdx.y >> 1) * 128;
    const int tid = threadIdx.x;
    const int tx = tid & 15;   // i-octet
    const int ty = tid >> 4;   // t-octet
    float acc[8][8];           // [c=t][a=i]
    #pragma unroll
    for (int c = 0; c < 8; ++c)
        #pragma unroll
        for (int a = 0; a < 8; ++a) acc[c][a] = 0.f;

    for (int dc = 0; dc < 256; dc += 64) {
        #pragma unroll
        for (int k = 0; k < 8; ++k) {
            int idx = k * 256 + tid;
            int row = idx >> 5, col4 = idx & 31;
            float4 yv = *(const float4*)&y[((size_t)b*256 + dc + row)*256 + t0 + col4*4];
            float4 wv = *(const float4*)&Wt[(size_t)(dc + row)*256 + i0 + col4*4];
            *(float4*)&ys[row][col4*4]  = yv;
            *(float4*)&wsh[row][col4*4] = wv;
        }
        __syncthreads();
        #pragma unroll 4
        for (int dd = 0; dd < 64; ++dd) {
            float4 w0 = *(const float4*)&wsh[dd][8*tx];
            float4 w1 = *(const float4*)&wsh[dd][8*tx+4];
            float4 y0 = *(const float4*)&ys[dd][8*ty];
            float4 y1 = *(const float4*)&ys[dd][8*ty+4];
            float wv[8] = {w0.x,w0.y,w0.z,w0.w,w1.x,w1.y,w1.z,w1.w};
            float yv[8] = {y0.x,y0.y,y0.z,y0.w,y1.x,y1.y,y1.z,y1.w};
            #pragma unroll
            for (int c = 0; c < 8; ++c)
                #pragma unroll
                for (int a = 0; a < 8; ++a) acc[c][a] += wv[a] * yv[c];
        }
        __syncthreads();
    }
    #pragma unroll
    for (int c = 0; c < 8; ++c) {
        int t = t0 + 8*ty + c;
        uint4 pk;
        pk.x = packh2(acc[c][0], acc[c][1]);
        pk.y = packh2(acc[c][2], acc[c][3]);
        pk.z = packh2(acc[c][4], acc[c][5]);
        pk.w = packh2(acc[c][6], acc[c][7]);
        *(uint4*)&Zh[((size_t)b*256 + t)*128 + (i0 >> 1) + 4*tx] = pk;
    }
}

// ---------------------------------------------------------------------------
// scan5: 256 blocks x 512 threads. Thread (i2 = tid>>2, q = tid&3) owns
// output rows 2i2, 2i2+1 and K-quarter q of both S and P (128 u32 in VGPRs;
// 2 waves/EU pinned -> 256-VGPR budget, no AGPR spill). Partial sums reduce
// across the quad with DPP quad_perm adds (no LDS, no extra barrier).
// 5 barriers/step total. Z fp16 in LDS; H flushed every 16 steps.
// ---------------------------------------------------------------------------
#define HQ_STRIDE 36   // u32 per K-quarter slot (32 data + 4 pad -> bank shift 4)

__global__ __attribute__((amdgpu_flat_work_group_size(512, 512),
                          amdgpu_waves_per_eu(2, 2)))
void scan5(const u32* __restrict__ Spk, const u32* __restrict__ Ppk,
           const u32* __restrict__ Zh,
           const float* __restrict__ h0, const float* __restrict__ U,
           const float* __restrict__ lam1p, const float* __restrict__ lam2p,
           const float* __restrict__ alphap,
           float* __restrict__ H) {
    __shared__ u32 Zl[32768];                         // 128 KB fp16 Z slice
    __shared__ float Hbuf[16 * DIMN];                 // 16 KB, 16 h columns
    __shared__ __align__(16) u32 hq[2][4 * HQ_STRIDE];// padded h (fp16 pairs)

    const int tid = threadIdx.x;
    const int q   = tid & 3;
    const int i2  = tid >> 2;
    const int b   = blockIdx.x;
    const int r0  = 2 * i2;
    const int qd  = i2 >> 5;          // which quarter rows r0,r0+1 live in
    const int wo  = i2 & 31;          // u32 offset inside that quarter

    const float inva = 1.0f / alphap[0];
    const float bt   = lam1p[0] * inva;
    const float c2   = lam2p[0] * inva;
    const float u0   = U[r0] * bt;
    const float u1   = U[r0 + 1] * bt;

    // matrix quarters -> VGPRs (coalesced b64 loads)
    u32 Sa[32], Sb[32], Pa[32], Pb[32];
    #pragma unroll
    for (int jp = 0; jp < 32; ++jp) {
        uint2 sv = *(const uint2*)&Spk[jp*1024 + 2*tid];
        uint2 pv = *(const uint2*)&Ppk[jp*1024 + 2*tid];
        Sa[jp] = sv.x; Sb[jp] = sv.y;
        Pa[jp] = pv.x; Pb[jp] = pv.y;
    }

    // preload Z slice (32768 u32)
    {
        const uint4* Zg = (const uint4*)(Zh + (size_t)b * 32768);
        uint4* Zd = (uint4*)Zl;
        #pragma unroll
        for (int k = 0; k < 16; ++k) Zd[k*512 + tid] = Zg[k*512 + tid];
    }
    if (q == 0) hq[0][qd*HQ_STRIDE + wo] = packh2(h0[r0], h0[r0+1]);
    __syncthreads();

    float* Hb = H + (size_t)b * TLEN * DIMN;

    int cur = 0;
    #pragma unroll 1
    for (int t = 0; t < TLEN; ++t) {
        // ---- P-phase ----
        {
            const u32* rp = &hq[cur][q*HQ_STRIDE];
            float a0=0.f, a1=0.f, c0=0.f, c1=0.f;
            #pragma unroll
            for (int k = 0; k < 8; ++k) {
                uint4 h4 = *(const uint4*)&rp[4*k];
                a0 = dot2f(Pa[4*k+0], h4.x, a0);
                a1 = dot2f(Pa[4*k+1], h4.y, a1);
                a0 = dot2f(Pa[4*k+2], h4.z, a0);
                a1 = dot2f(Pa[4*k+3], h4.w, a1);
                c0 = dot2f(Pb[4*k+0], h4.x, c0);
                c1 = dot2f(Pb[4*k+1], h4.y, c1);
                c0 = dot2f(Pb[4*k+2], h4.z, c0);
                c1 = dot2f(Pb[4*k+3], h4.w, c1);
            }
            float pa = quad_reduce(a0 + a1);
            float pb = quad_reduce(c0 + c1);
            u32 zc = Zl[t*128 + i2];
            float cst0 = h2lo(zc) + c2 * pa;
            float cst1 = h2hi(zc) + c2 * pb;
            if (q == 0) hq[cur ^ 1][qd*HQ_STRIDE + wo] = packh2(pa, pb);
            __syncthreads();

            // ---- 4 S-iterations ----
            int rbuf = cur ^ 1;
            #pragma unroll
            for (int it = 0; it < 4; ++it) {
                const u32* sp = &hq[rbuf][q*HQ_STRIDE];
                float s0=0.f, s1=0.f, s2=0.f, s3=0.f;
                #pragma unroll
                for (int k = 0; k < 8; ++k) {
                    uint4 h4 = *(const uint4*)&sp[4*k];
                    s0 = dot2f(Sa[4*k+0], h4.x, s0);
                    s1 = dot2f(Sa[4*k+1], h4.y, s1);
                    s0 = dot2f(Sa[4*k+2], h4.z, s0);
                    s1 = dot2f(Sa[4*k+3], h4.w, s1);
                    s2 = dot2f(Sb[4*k+0], h4.x, s2);
                    s3 = dot2f(Sb[4*k+1], h4.y, s3);
                    s2 = dot2f(Sb[4*k+2], h4.z, s2);
                    s3 = dot2f(Sb[4*k+3], h4.w, s3);
                }
                float za = quad_reduce(s0 + s1) + cst0;
                float zb = quad_reduce(s2 + s3) + cst1;
                float aa0 = fabsf(za) - u0;
                float aa1 = fabsf(zb) - u1;
                float hh0 = (aa0 > 0.f) ? copysignf(aa0, za) : 0.f;
                float hh1 = (aa1 > 0.f) ? copysignf(aa1, zb) : 0.f;
                if (q == 0) {
                    hq[rbuf ^ 1][qd*HQ_STRIDE + wo] = packh2(hh0, hh1);
                    if (it == 3)
                        *(float2*)&Hbuf[(t & 15)*DIMN + r0] = make_float2(hh0, hh1);
                }
                __syncthreads();
                rbuf ^= 1;
            }
        }
        cur ^= 1;   // final h_t buffer

        // ---- flush 16 completed h columns (coalesced float4, 1x/16 steps) ----
        if ((t & 15) == 15) {
            float4 v0 = *(const float4*)&Hbuf[tid*8];
            float4 v1 = *(const float4*)&Hbuf[tid*8 + 4];
            float* op = &Hb[(size_t)(t - 15) * DIMN + tid*8];
            *(float4*)(op)     = v0;
            *(float4*)(op + 4) = v1;
        }
    }
}

// ---------------------------------------------------------------------------
// out-GEMM: out[b][n][t] = sum_d D[n][d] * H[b][t][d]
// ---------------------------------------------------------------------------
__launch_bounds__(256, 2)
__global__ void ogemm(const float* __restrict__ D, const float* __restrict__ H,
                      float* __restrict__ out) {
    __shared__ float Ds[64][132];   // [dd][nn]
    __shared__ float Hs[64][132];   // [dd][tt]
    const int b  = blockIdx.x;
    const int n0 = (blockIdx.y & 1) * 128;
    const int t0 = (blockIdx.y >> 1) * 128;
    const int tid = threadIdx.x;
    const int tx = tid & 15;   // n-octet
    const int ty = tid >> 4;   // t-octet
    float acc[8][8];           // [a=n][c=t]
    #pragma unroll
    for (int a = 0; a < 8; ++a)
        #pragma unroll
        for (int c = 0; c < 8; ++c) acc[a][c] = 0.f;

    for (int dc = 0; dc < 256; dc += 64) {
        #pragma unroll
        for (int k = 0; k < 8; ++k) {
            int idx = k * 256 + tid;
            int row = idx >> 4;                // nn or tt (128 rows)
            int d4  = idx & 15;                // 16 float4 across d-chunk
            float4 dv = *(const float4*)&D[((size_t)(n0 + row))*256 + dc + d4*4];
            float4 hv = *(const float4*)&H[((size_t)b*256 + t0 + row)*256 + dc + d4*4];
            Ds[d4*4+0][row] = dv.x; Ds[d4*4+1][row] = dv.y;
            Ds[d4*4+2][row] = dv.z; Ds[d4*4+3][row] = dv.w;
            Hs[d4*4+0][row] = hv.x; Hs[d4*4+1][row] = hv.y;
            Hs[d4*4+2][row] = hv.z; Hs[d4*4+3][row] = hv.w;
        }
        __syncthreads();
        #pragma unroll 4
        for (int dd = 0; dd < 64; ++dd) {
            float4 d0 = *(const float4*)&Ds[dd][8*tx];
            float4 d1 = *(const float4*)&Ds[dd][8*tx+4];
            float4 h0v = *(const float4*)&Hs[dd][8*ty];
            float4 h1v = *(const float4*)&Hs[dd][8*ty+4];
            float dv[8] = {d0.x,d0.y,d0.z,d0.w,d1.x,d1.y,d1.z,d1.w};
            float hv[8] = {h0v.x,h0v.y,h0v.z,h0v.w,h1v.x,h1v.y,h1v.z,h1v.w};
            #pragma unroll
            for (int a = 0; a < 8; ++a)
                #pragma unroll
                for (int c = 0; c < 8; ++c) acc[a][c] += dv[a] * hv[c];
        }
        __syncthreads();
    }
    #pragma unroll
    for (int a = 0; a < 8; ++a) {
        float* op = &out[((size_t)b*256 + n0 + 8*tx + a)*256 + t0 + 8*ty];
        *(float4*)(op)     = make_float4(acc[a][0], acc[a][1], acc[a][2], acc[a][3]);
        *(float4*)(op + 4) = make_float4(acc[a][4], acc[a][5], acc[a][6], acc[a][7]);
    }
}

// ---------------------------------------------------------------------------
extern "C" void kernel_launch(void* const* d_in, const int* in_sizes, int n_in,
                              void* d_out, int out_size, void* d_ws, size_t ws_size,
                              hipStream_t stream) {
    const float* y     = (const float*)d_in[0];
    const float* A     = (const float*)d_in[1];
    const float* D     = (const float*)d_in[2];
    const float* F     = (const float*)d_in[3];
    const float* lam1  = (const float*)d_in[4];
    const float* lam2  = (const float*)d_in[5];
    const float* alpha = (const float*)d_in[6];
    const float* h0    = (const float*)d_in[7];
    const float* U     = (const float*)d_in[8];
    float* out = (float*)d_out;
    float* ws  = (float*)d_ws;

    // ws layout (fp32-element offsets)
    const size_t oZ  = 0;           // Zh: 8.39M u32 packed fp16 (region 16.7M)
    const size_t oH  = 16777216;    // H fp32: 16.7M
    const size_t oWt = 33554432;
    const size_t oSt = 33619968;
    const size_t oPt = 33685504;
    const size_t oFD = 33751040;
    const size_t oG  = 33816576;
    const size_t oGD = 33882112;
    const size_t oAD = 33947648;
    const size_t oSh = 33964032;   // Spk u32 (32768)
    const size_t oPh = 33996800;   // Ppk u32 (32768)

    u32*   Zh = (u32*)(ws + oZ);
    float* H  = ws + oH;
    float* Wt = ws + oWt; float* St = ws + oSt; float* Pt = ws + oPt;
    float* FD = ws + oFD; float* G  = ws + oG;  float* GD = ws + oGD;
    float* AD = ws + oAD;
    u32* Spk = (u32*)(ws + oSh);
    u32* Ppk = (u32*)(ws + oPh);

    prep1<<<576, 256, 0, stream>>>(A, D, F, lam2, FD, G, AD);
    prep2<<<768, 256, 0, stream>>>(A, D, alpha, FD, G, AD, Pt, GD, Wt);
    prep3<<<256, 256, 0, stream>>>(D, GD, alpha, St);
    prep4<<<256, 256, 0, stream>>>(St, Pt, Spk, Ppk);
    {
        dim3 g(256, 4);
        zgemm<<<g, 256, 0, stream>>>(y, Wt, Zh);
    }
    scan5<<<256, 512, 0, stream>>>(Spk, Ppk, Zh, h0, U, lam1, lam2, alpha, H);
    {
        dim3 g(256, 4);
        ogemm<<<g, 256, 0, stream>>>(D, H, out);
    }
}